// Round 5
// baseline (236.156 us; speedup 1.0000x reference)
//
#include <hip/hip_runtime.h>

// LightGCN extractor, round 5:
//  - edge list radix-partitioned into 8 XCD slices in ONE pass (LDS counters + scan)
//  - slice-local hist/fill (sequential reads, XCD-L2-resident atomics/writes)
//  - bf16 node tables, unroll-8 gathers, layer 3 fused into output kernel

#define STU 100000
#define EXER 50000
#define KNOW 123
#define DIM 64
#define N_NODES 150000
#define N_EDGES 1200000
#define NB 8192
#define NSCAN_BLOCKS 586       // ceil(150000/256)
#define NSLICE 8
#define ROWS_PER_SLICE 18750   // 150000/8
#define PBLK 1024              // partition blocks
#define PCHUNK 1172            // ceil(N_EDGES/PBLK)
#define HBLK2 2048             // 256 blocks per slice for hist2/fill2

typedef unsigned short bfu;

static const long long NODE_F = (long long)N_NODES * DIM;  // 9.6M elems

__device__ __forceinline__ bfu f2bf(float f) {
    unsigned int u = __float_as_uint(f);
    unsigned int r = (u + 0x7FFFu + ((u >> 16) & 1u)) >> 16;   // RNE
    return (bfu)r;
}
__device__ __forceinline__ float bf2f(bfu h) {
    return __uint_as_float((unsigned int)h << 16);
}

// ---- h0 concat -> bf16 table ----
__global__ void k_conv0(const float* __restrict__ stu, const float* __restrict__ exer,
                        bfu* __restrict__ b0) {
    long long i = (long long)blockIdx.x * blockDim.x + threadIdx.x;  // float4 index
    long long n4 = NODE_F >> 2;
    if (i >= n4) return;
    long long stu4 = ((long long)STU * DIM) >> 2;
    float4 v = (i < stu4) ? ((const float4*)stu)[i]
                          : ((const float4*)exer)[i - stu4];
    ushort4 o;
    o.x = f2bf(v.x); o.y = f2bf(v.y); o.z = f2bf(v.z); o.w = f2bf(v.w);
    ((ushort4*)b0)[i] = o;
}

// ---- pass A: partition edges into 8 slice-contiguous regions ----
__global__ void k_phist(const int* __restrict__ erow, int* __restrict__ pcnt) {
    __shared__ int cnt[NSLICE];
    if (threadIdx.x < NSLICE) cnt[threadIdx.x] = 0;
    __syncthreads();
    int b = blockIdx.x;
    long long s = (long long)b * PCHUNK;
    long long e = s + PCHUNK; if (e > N_EDGES) e = N_EDGES;
    for (long long k = s + threadIdx.x; k < e; k += blockDim.x)
        atomicAdd(&cnt[erow[k] / ROWS_PER_SLICE], 1);
    __syncthreads();
    if (threadIdx.x < NSLICE)
        pcnt[threadIdx.x * PBLK + b] = cnt[threadIdx.x];   // slice-major
}

// exclusive scan of 8192 ints, 1 block x 1024 threads x 8 each
__global__ void k_pscan(const int* __restrict__ pcnt, int* __restrict__ pcntoff) {
    __shared__ int s[1024];
    int t = threadIdx.x;
    int v[8]; int sum = 0;
#pragma unroll
    for (int j = 0; j < 8; j++) { v[j] = pcnt[t * 8 + j]; sum += v[j]; }
    s[t] = sum;
    __syncthreads();
    for (int o = 1; o < 1024; o <<= 1) {
        int x = (t >= o) ? s[t - o] : 0;
        __syncthreads();
        s[t] += x;
        __syncthreads();
    }
    int excl = s[t] - sum;
#pragma unroll
    for (int j = 0; j < 8; j++) { pcntoff[t * 8 + j] = excl; excl += v[j]; }
}

__global__ void k_ppart(const int* __restrict__ erow, const int* __restrict__ ecol,
                        const float* __restrict__ eval, const int* __restrict__ pcntoff,
                        int* __restrict__ prow, int2* __restrict__ pcv) {
    __shared__ int base[NSLICE];
    int b = blockIdx.x;
    if (threadIdx.x < NSLICE) base[threadIdx.x] = pcntoff[threadIdx.x * PBLK + b];
    __syncthreads();
    long long s = (long long)b * PCHUNK;
    long long e = s + PCHUNK; if (e > N_EDGES) e = N_EDGES;
    for (long long k = s + threadIdx.x; k < e; k += blockDim.x) {
        int r = erow[k];
        int p = atomicAdd(&base[r / ROWS_PER_SLICE], 1);
        prow[p] = r;
        pcv[p] = make_int2(ecol[k], __float_as_int(eval[k]));
    }
}

// ---- pass B: slice-local hist / fill (blockIdx&7 -> XCD) ----
__global__ void k_hist2(const int* __restrict__ prow, const int* __restrict__ pcntoff,
                        int* __restrict__ deg) {
    int slice = blockIdx.x & (NSLICE - 1);
    int sub = blockIdx.x >> 3;
    int nsub = gridDim.x >> 3;
    int rs = pcntoff[slice * PBLK];
    int re = (slice == NSLICE - 1) ? N_EDGES : pcntoff[(slice + 1) * PBLK];
    for (int k = rs + sub * blockDim.x + threadIdx.x; k < re; k += nsub * blockDim.x)
        atomicAdd(&deg[prow[k]], 1);
}

__global__ void k_scan1(const int* __restrict__ deg, int* __restrict__ off,
                        int* __restrict__ bsum) {
    __shared__ int s[256];
    int i = blockIdx.x * 256 + threadIdx.x;
    int v = (i < N_NODES) ? deg[i] : 0;
    s[threadIdx.x] = v;
    __syncthreads();
    for (int o = 1; o < 256; o <<= 1) {
        int x = (threadIdx.x >= o) ? s[threadIdx.x - o] : 0;
        __syncthreads();
        s[threadIdx.x] += x;
        __syncthreads();
    }
    if (i < N_NODES) off[i] = s[threadIdx.x] - v;
    if (threadIdx.x == 255) bsum[blockIdx.x] = s[255];
}

__global__ void k_scan2(const int* __restrict__ bsum, int* __restrict__ bsumoff) {
    __shared__ int s[1024];
    int t = threadIdx.x;
    int v = (t < NSCAN_BLOCKS) ? bsum[t] : 0;
    s[t] = v;
    __syncthreads();
    for (int o = 1; o < 1024; o <<= 1) {
        int x = (t >= o) ? s[t - o] : 0;
        __syncthreads();
        s[t] += x;
        __syncthreads();
    }
    if (t < NSCAN_BLOCKS) bsumoff[t] = s[t] - v;
}

__global__ void k_scan3(int* __restrict__ off, int* __restrict__ cur,
                        const int* __restrict__ bsumoff) {
    int i = blockIdx.x * 256 + threadIdx.x;
    if (i < N_NODES) {
        int v = off[i] + bsumoff[i >> 8];
        off[i] = v;
        cur[i] = v;
    }
    if (i == 0) off[N_NODES] = N_EDGES;
}

__global__ void k_fill2(const int* __restrict__ prow, const int2* __restrict__ pcv,
                        const int* __restrict__ pcntoff,
                        int* __restrict__ cur, int2* __restrict__ sedge) {
    int slice = blockIdx.x & (NSLICE - 1);
    int sub = blockIdx.x >> 3;
    int nsub = gridDim.x >> 3;
    int rs = pcntoff[slice * PBLK];
    int re = (slice == NSLICE - 1) ? N_EDGES : pcntoff[(slice + 1) * PBLK];
    for (int k = rs + sub * blockDim.x + threadIdx.x; k < re; k += nsub * blockDim.x) {
        int p = atomicAdd(&cur[prow[k]], 1);
        sedge[p] = pcv[k];
    }
}

// ---- gather layer: wave per node, lane per dim, bf16 in/out ----
__global__ void k_gather_bf(const int* __restrict__ off, const int2* __restrict__ sedge,
                            const bfu* __restrict__ h, bfu* __restrict__ out) {
    int w = (blockIdx.x * blockDim.x + threadIdx.x) >> 6;
    int lane = threadIdx.x & 63;
    if (w >= N_NODES) return;
    int wu = __builtin_amdgcn_readfirstlane(w);
    int s = off[wu], e = off[wu + 1];
    float acc = 0.f;
    int k = s;
    for (; k + 8 <= e; k += 8) {
        int2 ev[8];
#pragma unroll
        for (int j = 0; j < 8; j++) ev[j] = sedge[k + j];
        float a[8];
#pragma unroll
        for (int j = 0; j < 8; j++) a[j] = bf2f(h[(long long)ev[j].x * DIM + lane]);
#pragma unroll
        for (int j = 0; j < 8; j++) acc += __int_as_float(ev[j].y) * a[j];
    }
    for (; k + 4 <= e; k += 4) {
        int2 ev[4];
#pragma unroll
        for (int j = 0; j < 4; j++) ev[j] = sedge[k + j];
        float a[4];
#pragma unroll
        for (int j = 0; j < 4; j++) a[j] = bf2f(h[(long long)ev[j].x * DIM + lane]);
#pragma unroll
        for (int j = 0; j < 4; j++) acc += __int_as_float(ev[j].y) * a[j];
    }
    for (; k < e; k++) {
        int2 ev = sedge[k];
        acc += __int_as_float(ev.y) * bf2f(h[(long long)ev.x * DIM + lane]);
    }
    out[(long long)wu * DIM + lane] = f2bf(acc);
}

// ---- outputs: layer-3 gather over B2 fused ----
__global__ void k_out_main(const int* __restrict__ sid, const int* __restrict__ eid,
                           const int* __restrict__ off, const int2* __restrict__ sedge,
                           const float* __restrict__ stu, const float* __restrict__ exer,
                           const bfu* __restrict__ B1, const bfu* __restrict__ B2,
                           float* __restrict__ out) {
    int w = (blockIdx.x * blockDim.x + threadIdx.x) >> 6;
    int lane = threadIdx.x & 63;
    if (w >= 2 * NB) return;
    int wu = __builtin_amdgcn_readfirstlane(w);
    int r;
    long long obase;
    if (wu < NB) { r = sid[wu];            obase = (long long)wu * 64; }
    else         { r = STU + eid[wu - NB]; obase = 524288 + (long long)(wu - NB) * 64; }
    int ru = __builtin_amdgcn_readfirstlane(r);
    long long rb = (long long)ru * 64 + lane;
    float h0 = (ru < STU) ? stu[rb] : exer[rb - (long long)STU * 64];
    float s = h0 + bf2f(B1[rb]) + bf2f(B2[rb]);
    int st = off[ru], en = off[ru + 1];
    float g = 0.f;
    int k = st;
    for (; k + 8 <= en; k += 8) {
        int2 ev[8];
#pragma unroll
        for (int j = 0; j < 8; j++) ev[j] = sedge[k + j];
        float a[8];
#pragma unroll
        for (int j = 0; j < 8; j++) a[j] = bf2f(B2[(long long)ev[j].x * DIM + lane]);
#pragma unroll
        for (int j = 0; j < 8; j++) g += __int_as_float(ev[j].y) * a[j];
    }
    for (; k < en; k++) {
        int2 ev = sedge[k];
        g += __int_as_float(ev.y) * bf2f(B2[(long long)ev.x * DIM + lane]);
    }
    out[obase + lane] = 0.25f * (s + g);
}

__global__ void k_out_tail(const int* __restrict__ eid, const float* __restrict__ disc,
                           const float* __restrict__ know, float* __restrict__ out) {
    int i = blockIdx.x * blockDim.x + threadIdx.x;
    if (i < NB) out[1048576 + i] = disc[eid[i]];
    else if (i < NB + KNOW * DIM) out[1056768 + (i - NB)] = know[i - NB];
}

extern "C" void kernel_launch(void* const* d_in, const int* in_sizes, int n_in,
                              void* d_out, int out_size, void* d_ws, size_t ws_size,
                              hipStream_t stream) {
    const int*   sid  = (const int*)d_in[0];
    const int*   eid  = (const int*)d_in[1];
    const int*   erow = (const int*)d_in[3];
    const int*   ecol = (const int*)d_in[4];
    const float* eval = (const float*)d_in[5];
    const float* stu  = (const float*)d_in[6];
    const float* exer = (const float*)d_in[7];
    const float* disc = (const float*)d_in[8];
    const float* know = (const float*)d_in[9];
    float* out = (float*)d_out;

    char* ws = (char*)d_ws;
    bfu*  B0      = (bfu*) (ws);                      // 19.2 MB
    bfu*  B1      = (bfu*) (ws + 19200000);           // 19.2 MB
    bfu*  B2      = (bfu*) (ws + 38400000);           // 19.2 MB
    int*  off     = (int*) (ws + 57600000);           // 600,004 B
    int*  deg     = (int*) (ws + 58200064);           // 600,000 B
    int*  cur     = (int*) (ws + 58800064);           // 600,000 B
    int*  bsum    = (int*) (ws + 59400064);           // 2,344 B
    int*  bsumoff = (int*) (ws + 59402432);           // 2,344 B
    int2* sedge   = (int2*)(ws + 59404800);           // 9.6 MB
    int*  prow    = (int*) (ws + 69004800);           // 4.8 MB
    int2* pcv     = (int2*)(ws + 73805312);           // 9.6 MB
    int*  pcnt    = (int*) (ws + 83406336);           // 32 KB
    int*  pcntoff = (int*) (ws + 83439104);           // 32 KB  (ends ~83.5 MB)

    const int BLK = 256;
    long long n4 = NODE_F >> 2;
    int convGrid = (int)((n4 + BLK - 1) / BLK);
    int nodeWaveGrid = (int)(((long long)N_NODES * 64 + BLK - 1) / BLK);  // 37500
    int outMainGrid = (2 * NB * 64) / BLK;
    int outTailGrid = (NB + KNOW * DIM + BLK - 1) / BLK;

    // h0 -> bf16 table
    k_conv0<<<convGrid, BLK, 0, stream>>>(stu, exer, B0);

    // pass A: partition edges by row-slice
    k_phist<<<PBLK, BLK, 0, stream>>>(erow, pcnt);
    k_pscan<<<1, 1024, 0, stream>>>(pcnt, pcntoff);
    k_ppart<<<PBLK, BLK, 0, stream>>>(erow, ecol, eval, pcntoff, prow, pcv);

    // pass B: slice-local CSR build
    hipMemsetAsync(deg, 0, N_NODES * sizeof(int), stream);
    k_hist2<<<HBLK2, BLK, 0, stream>>>(prow, pcntoff, deg);
    k_scan1<<<NSCAN_BLOCKS, BLK, 0, stream>>>(deg, off, bsum);
    k_scan2<<<1, 1024, 0, stream>>>(bsum, bsumoff);
    k_scan3<<<NSCAN_BLOCKS, BLK, 0, stream>>>(off, cur, bsumoff);
    k_fill2<<<HBLK2, BLK, 0, stream>>>(prow, pcv, pcntoff, cur, sedge);

    // layers 1,2
    k_gather_bf<<<nodeWaveGrid, BLK, 0, stream>>>(off, sedge, B0, B1);
    k_gather_bf<<<nodeWaveGrid, BLK, 0, stream>>>(off, sedge, B1, B2);

    // layer 3 fused into outputs
    k_out_main<<<outMainGrid, BLK, 0, stream>>>(sid, eid, off, sedge, stu, exer, B1, B2, out);
    k_out_tail<<<outTailGrid, BLK, 0, stream>>>(eid, disc, know, out);
}

// Round 6
// 232.360 us; speedup vs baseline: 1.0163x; 1.0163x over previous
//
#include <hip/hip_runtime.h>

// LightGCN extractor, round 6:
//  - non-temporal streaming reads in partition/fill (stop L2-thrashing scatter lines)
//  - deg histogram folded into ppart (k_hist2 deleted)
//  - edge list radix-partitioned into 8 XCD slices, slice-local CSR fill
//  - bf16 node tables, unroll-8 gathers, layer 3 fused into output kernel

#define STU 100000
#define EXER 50000
#define KNOW 123
#define DIM 64
#define N_NODES 150000
#define N_EDGES 1200000
#define NB 8192
#define NSCAN_BLOCKS 586       // ceil(150000/256)
#define NSLICE 8
#define ROWS_PER_SLICE 18750   // 150000/8
#define PBLK 1024              // partition blocks
#define PCHUNK 1172            // ceil(N_EDGES/PBLK)
#define FBLK 2048              // 256 blocks per slice for fill

typedef unsigned short bfu;

static const long long NODE_F = (long long)N_NODES * DIM;  // 9.6M elems

__device__ __forceinline__ bfu f2bf(float f) {
    unsigned int u = __float_as_uint(f);
    unsigned int r = (u + 0x7FFFu + ((u >> 16) & 1u)) >> 16;   // RNE
    return (bfu)r;
}
__device__ __forceinline__ float bf2f(bfu h) {
    return __uint_as_float((unsigned int)h << 16);
}
__device__ __forceinline__ long long nt_i64(const void* p) {
    return __builtin_nontemporal_load((const long long*)p);
}

// ---- h0 concat -> bf16 table ----
__global__ void k_conv0(const float* __restrict__ stu, const float* __restrict__ exer,
                        bfu* __restrict__ b0) {
    long long i = (long long)blockIdx.x * blockDim.x + threadIdx.x;  // float4 index
    long long n4 = NODE_F >> 2;
    if (i >= n4) return;
    long long stu4 = ((long long)STU * DIM) >> 2;
    float4 v = (i < stu4) ? ((const float4*)stu)[i]
                          : ((const float4*)exer)[i - stu4];
    ushort4 o;
    o.x = f2bf(v.x); o.y = f2bf(v.y); o.z = f2bf(v.z); o.w = f2bf(v.w);
    ((ushort4*)b0)[i] = o;
}

// ---- pass A: partition edges into 8 slice-contiguous regions ----
__global__ void k_phist(const int* __restrict__ erow, int* __restrict__ pcnt) {
    __shared__ int cnt[NSLICE];
    if (threadIdx.x < NSLICE) cnt[threadIdx.x] = 0;
    __syncthreads();
    int b = blockIdx.x;
    long long s = (long long)b * PCHUNK;
    long long e = s + PCHUNK; if (e > N_EDGES) e = N_EDGES;
    for (long long k = s + threadIdx.x; k < e; k += blockDim.x) {
        int r = __builtin_nontemporal_load(&erow[k]);
        atomicAdd(&cnt[r / ROWS_PER_SLICE], 1);
    }
    __syncthreads();
    if (threadIdx.x < NSLICE)
        pcnt[threadIdx.x * PBLK + b] = cnt[threadIdx.x];   // slice-major
}

// exclusive scan of 8192 ints, 1 block x 1024 threads x 8 each
__global__ void k_pscan(const int* __restrict__ pcnt, int* __restrict__ pcntoff) {
    __shared__ int s[1024];
    int t = threadIdx.x;
    int v[8]; int sum = 0;
#pragma unroll
    for (int j = 0; j < 8; j++) { v[j] = pcnt[t * 8 + j]; sum += v[j]; }
    s[t] = sum;
    __syncthreads();
    for (int o = 1; o < 1024; o <<= 1) {
        int x = (t >= o) ? s[t - o] : 0;
        __syncthreads();
        s[t] += x;
        __syncthreads();
    }
    int excl = s[t] - sum;
#pragma unroll
    for (int j = 0; j < 8; j++) { pcntoff[t * 8 + j] = excl; excl += v[j]; }
}

// partition + per-row degree histogram (deg atomics execute memory-side)
__global__ void k_ppart(const int* __restrict__ erow, const int* __restrict__ ecol,
                        const float* __restrict__ eval, const int* __restrict__ pcntoff,
                        int* __restrict__ prow, int2* __restrict__ pcv,
                        int* __restrict__ deg) {
    __shared__ int base[NSLICE];
    int b = blockIdx.x;
    if (threadIdx.x < NSLICE) base[threadIdx.x] = pcntoff[threadIdx.x * PBLK + b];
    __syncthreads();
    long long s = (long long)b * PCHUNK;
    long long e = s + PCHUNK; if (e > N_EDGES) e = N_EDGES;
    for (long long k = s + threadIdx.x; k < e; k += blockDim.x) {
        int r = __builtin_nontemporal_load(&erow[k]);
        int c = __builtin_nontemporal_load(&ecol[k]);
        float v = __builtin_nontemporal_load(&eval[k]);
        int p = atomicAdd(&base[r / ROWS_PER_SLICE], 1);
        prow[p] = r;
        pcv[p] = make_int2(c, __float_as_int(v));
        atomicAdd(&deg[r], 1);
    }
}

__global__ void k_scan1(const int* __restrict__ deg, int* __restrict__ off,
                        int* __restrict__ bsum) {
    __shared__ int s[256];
    int i = blockIdx.x * 256 + threadIdx.x;
    int v = (i < N_NODES) ? deg[i] : 0;
    s[threadIdx.x] = v;
    __syncthreads();
    for (int o = 1; o < 256; o <<= 1) {
        int x = (threadIdx.x >= o) ? s[threadIdx.x - o] : 0;
        __syncthreads();
        s[threadIdx.x] += x;
        __syncthreads();
    }
    if (i < N_NODES) off[i] = s[threadIdx.x] - v;
    if (threadIdx.x == 255) bsum[blockIdx.x] = s[255];
}

__global__ void k_scan2(const int* __restrict__ bsum, int* __restrict__ bsumoff) {
    __shared__ int s[1024];
    int t = threadIdx.x;
    int v = (t < NSCAN_BLOCKS) ? bsum[t] : 0;
    s[t] = v;
    __syncthreads();
    for (int o = 1; o < 1024; o <<= 1) {
        int x = (t >= o) ? s[t - o] : 0;
        __syncthreads();
        s[t] += x;
        __syncthreads();
    }
    if (t < NSCAN_BLOCKS) bsumoff[t] = s[t] - v;
}

__global__ void k_scan3(int* __restrict__ off, int* __restrict__ cur,
                        const int* __restrict__ bsumoff) {
    int i = blockIdx.x * 256 + threadIdx.x;
    if (i < N_NODES) {
        int v = off[i] + bsumoff[i >> 8];
        off[i] = v;
        cur[i] = v;
    }
    if (i == 0) off[N_NODES] = N_EDGES;
}

// slice-local CSR fill: nt reads so sedge scatter lines stay L2-resident
__global__ void k_fill2(const int* __restrict__ prow, const int2* __restrict__ pcv,
                        const int* __restrict__ pcntoff,
                        int* __restrict__ cur, long long* __restrict__ sedge) {
    int slice = blockIdx.x & (NSLICE - 1);
    int sub = blockIdx.x >> 3;
    int nsub = gridDim.x >> 3;
    int rs = pcntoff[slice * PBLK];
    int re = (slice == NSLICE - 1) ? N_EDGES : pcntoff[(slice + 1) * PBLK];
    for (int k = rs + sub * blockDim.x + threadIdx.x; k < re; k += nsub * blockDim.x) {
        int r = __builtin_nontemporal_load(&prow[k]);
        long long cv = nt_i64(&pcv[k]);
        int p = atomicAdd(&cur[r], 1);
        sedge[p] = cv;                      // cached store, line fills in L2
    }
}

// ---- gather layer: wave per node, lane per dim, bf16 in/out ----
__global__ void k_gather_bf(const int* __restrict__ off, const long long* __restrict__ sedge,
                            const bfu* __restrict__ h, bfu* __restrict__ out) {
    int w = (blockIdx.x * blockDim.x + threadIdx.x) >> 6;
    int lane = threadIdx.x & 63;
    if (w >= N_NODES) return;
    int wu = __builtin_amdgcn_readfirstlane(w);
    int s = off[wu], e = off[wu + 1];
    float acc = 0.f;
    int k = s;
    for (; k + 8 <= e; k += 8) {
        long long ev[8];
#pragma unroll
        for (int j = 0; j < 8; j++) ev[j] = nt_i64(&sedge[k + j]);
        float a[8];
#pragma unroll
        for (int j = 0; j < 8; j++) a[j] = bf2f(h[(long long)(int)ev[j] * DIM + lane]);
#pragma unroll
        for (int j = 0; j < 8; j++) acc += __int_as_float((int)(ev[j] >> 32)) * a[j];
    }
    for (; k + 4 <= e; k += 4) {
        long long ev[4];
#pragma unroll
        for (int j = 0; j < 4; j++) ev[j] = nt_i64(&sedge[k + j]);
        float a[4];
#pragma unroll
        for (int j = 0; j < 4; j++) a[j] = bf2f(h[(long long)(int)ev[j] * DIM + lane]);
#pragma unroll
        for (int j = 0; j < 4; j++) acc += __int_as_float((int)(ev[j] >> 32)) * a[j];
    }
    for (; k < e; k++) {
        long long ev = nt_i64(&sedge[k]);
        acc += __int_as_float((int)(ev >> 32)) * bf2f(h[(long long)(int)ev * DIM + lane]);
    }
    out[(long long)wu * DIM + lane] = f2bf(acc);
}

// ---- outputs: layer-3 gather over B2 fused ----
__global__ void k_out_main(const int* __restrict__ sid, const int* __restrict__ eid,
                           const int* __restrict__ off, const long long* __restrict__ sedge,
                           const float* __restrict__ stu, const float* __restrict__ exer,
                           const bfu* __restrict__ B1, const bfu* __restrict__ B2,
                           float* __restrict__ out) {
    int w = (blockIdx.x * blockDim.x + threadIdx.x) >> 6;
    int lane = threadIdx.x & 63;
    if (w >= 2 * NB) return;
    int wu = __builtin_amdgcn_readfirstlane(w);
    int r;
    long long obase;
    if (wu < NB) { r = sid[wu];            obase = (long long)wu * 64; }
    else         { r = STU + eid[wu - NB]; obase = 524288 + (long long)(wu - NB) * 64; }
    int ru = __builtin_amdgcn_readfirstlane(r);
    long long rb = (long long)ru * 64 + lane;
    float h0 = (ru < STU) ? stu[rb] : exer[rb - (long long)STU * 64];
    float s = h0 + bf2f(B1[rb]) + bf2f(B2[rb]);
    int st = off[ru], en = off[ru + 1];
    float g = 0.f;
    int k = st;
    for (; k + 8 <= en; k += 8) {
        long long ev[8];
#pragma unroll
        for (int j = 0; j < 8; j++) ev[j] = nt_i64(&sedge[k + j]);
        float a[8];
#pragma unroll
        for (int j = 0; j < 8; j++) a[j] = bf2f(B2[(long long)(int)ev[j] * DIM + lane]);
#pragma unroll
        for (int j = 0; j < 8; j++) g += __int_as_float((int)(ev[j] >> 32)) * a[j];
    }
    for (; k < en; k++) {
        long long ev = nt_i64(&sedge[k]);
        g += __int_as_float((int)(ev >> 32)) * bf2f(B2[(long long)(int)ev * DIM + lane]);
    }
    out[obase + lane] = 0.25f * (s + g);
}

__global__ void k_out_tail(const int* __restrict__ eid, const float* __restrict__ disc,
                           const float* __restrict__ know, float* __restrict__ out) {
    int i = blockIdx.x * blockDim.x + threadIdx.x;
    if (i < NB) out[1048576 + i] = disc[eid[i]];
    else if (i < NB + KNOW * DIM) out[1056768 + (i - NB)] = know[i - NB];
}

extern "C" void kernel_launch(void* const* d_in, const int* in_sizes, int n_in,
                              void* d_out, int out_size, void* d_ws, size_t ws_size,
                              hipStream_t stream) {
    const int*   sid  = (const int*)d_in[0];
    const int*   eid  = (const int*)d_in[1];
    const int*   erow = (const int*)d_in[3];
    const int*   ecol = (const int*)d_in[4];
    const float* eval = (const float*)d_in[5];
    const float* stu  = (const float*)d_in[6];
    const float* exer = (const float*)d_in[7];
    const float* disc = (const float*)d_in[8];
    const float* know = (const float*)d_in[9];
    float* out = (float*)d_out;

    char* ws = (char*)d_ws;
    bfu*       B0      = (bfu*)      (ws);                // 19.2 MB
    bfu*       B1      = (bfu*)      (ws + 19200000);     // 19.2 MB
    bfu*       B2      = (bfu*)      (ws + 38400000);     // 19.2 MB
    int*       off     = (int*)      (ws + 57600000);     // 600,004 B
    int*       deg     = (int*)      (ws + 58200064);     // 600,000 B
    int*       cur     = (int*)      (ws + 58800064);     // 600,000 B
    int*       bsum    = (int*)      (ws + 59400064);     // 2,344 B
    int*       bsumoff = (int*)      (ws + 59402432);     // 2,344 B
    long long* sedge   = (long long*)(ws + 59404800);     // 9.6 MB
    int*       prow    = (int*)      (ws + 69004800);     // 4.8 MB
    int2*      pcv     = (int2*)     (ws + 73805312);     // 9.6 MB
    int*       pcnt    = (int*)      (ws + 83406336);     // 32 KB
    int*       pcntoff = (int*)      (ws + 83439104);     // 32 KB (ends ~83.5 MB)

    const int BLK = 256;
    long long n4 = NODE_F >> 2;
    int convGrid = (int)((n4 + BLK - 1) / BLK);
    int nodeWaveGrid = (int)(((long long)N_NODES * 64 + BLK - 1) / BLK);  // 37500
    int outMainGrid = (2 * NB * 64) / BLK;
    int outTailGrid = (NB + KNOW * DIM + BLK - 1) / BLK;

    // h0 -> bf16 table
    k_conv0<<<convGrid, BLK, 0, stream>>>(stu, exer, B0);

    // pass A: partition edges by row-slice (+ per-row degree)
    hipMemsetAsync(deg, 0, N_NODES * sizeof(int), stream);
    k_phist<<<PBLK, BLK, 0, stream>>>(erow, pcnt);
    k_pscan<<<1, 1024, 0, stream>>>(pcnt, pcntoff);
    k_ppart<<<PBLK, BLK, 0, stream>>>(erow, ecol, eval, pcntoff, prow, pcv, deg);

    // offsets + slice-local fill
    k_scan1<<<NSCAN_BLOCKS, BLK, 0, stream>>>(deg, off, bsum);
    k_scan2<<<1, 1024, 0, stream>>>(bsum, bsumoff);
    k_scan3<<<NSCAN_BLOCKS, BLK, 0, stream>>>(off, cur, bsumoff);
    k_fill2<<<FBLK, BLK, 0, stream>>>(prow, pcv, pcntoff, cur, sedge);

    // layers 1,2
    k_gather_bf<<<nodeWaveGrid, BLK, 0, stream>>>(off, sedge, B0, B1);
    k_gather_bf<<<nodeWaveGrid, BLK, 0, stream>>>(off, sedge, B1, B2);

    // layer 3 fused into outputs
    k_out_main<<<outMainGrid, BLK, 0, stream>>>(sid, eid, off, sedge, stu, exer, B1, B2, out);
    k_out_tail<<<outTailGrid, BLK, 0, stream>>>(eid, disc, know, out);
}